// Round 3
// baseline (618.714 us; speedup 1.0000x reference)
//
#include <hip/hip_runtime.h>
#include <math.h>

#define NNODES 50000
#define NEDGES 800000
#define KIN 1024
#define DH 128

typedef __bf16 bf16x8 __attribute__((ext_vector_type(8)));
typedef float floatx4 __attribute__((ext_vector_type(4)));

// ---------------- CSR build ----------------
__global__ void k_zero2(int* __restrict__ a, int* __restrict__ b, int n) {
  int i = blockIdx.x * blockDim.x + threadIdx.x;
  if (i < n) { a[i] = 0; b[i] = 0; }
}

__global__ void k_hist(const int* __restrict__ dst, int* __restrict__ cnt, int E) {
  int i = blockIdx.x * blockDim.x + threadIdx.x;
  if (i < E) atomicAdd(&cnt[dst[i]], 1);
}

// hierarchical scan: per-block 1024-elem scan + block sums
__global__ __launch_bounds__(1024) void k_scan_local(const int* __restrict__ cnt,
                                                     int* __restrict__ row_ptr,
                                                     int* __restrict__ bsum, int n) {
  __shared__ int sd[1024];
  int t = threadIdx.x;
  int i = blockIdx.x * 1024 + t;
  int v = (i < n) ? cnt[i] : 0;
  sd[t] = v;
  __syncthreads();
  for (int off = 1; off < 1024; off <<= 1) {
    int tv = (t >= off) ? sd[t - off] : 0;
    __syncthreads();
    sd[t] += tv;
    __syncthreads();
  }
  if (i < n) row_ptr[i] = sd[t] - v;  // exclusive within block
  if (t == 1023) bsum[blockIdx.x] = sd[t];
}

// one wave scans the <=64 block sums; writes exclusive offsets + grand total
__global__ void k_scan_sums(const int* __restrict__ bsum, int* __restrict__ boff,
                            int nb, int* __restrict__ row_ptr, int n) {
  int lane = threadIdx.x;  // 64 threads
  int v = (lane < nb) ? bsum[lane] : 0;
  int incl = v;
  for (int off = 1; off < 64; off <<= 1) {
    int t = __shfl_up(incl, off);
    if (lane >= off) incl += t;
  }
  boff[lane] = incl - v;
  if (lane == 63) row_ptr[n] = incl;
}

__global__ void k_scan_add(int* __restrict__ row_ptr, const int* __restrict__ boff, int n) {
  int i = blockIdx.x * blockDim.x + threadIdx.x;
  if (i < n) row_ptr[i] += boff[i >> 10];
}

__global__ void k_fill(const int* __restrict__ src, const int* __restrict__ dst,
                       const int* __restrict__ row_ptr, int* __restrict__ cursor,
                       int* __restrict__ csr_src, int E) {
  int i = blockIdx.x * blockDim.x + threadIdx.x;
  if (i < E) {
    int d = dst[i];
    int pos = row_ptr[d] + atomicAdd(&cursor[d], 1);
    csr_src[pos] = src[i];
  }
}

// ---------------- B pre-convert: Bt[256][K] bf16, Bt[n][k] = (W|Wr)[k][n] ----------------
__global__ __launch_bounds__(256) void k_prepB(const float* __restrict__ W,
                                               const float* __restrict__ Wr,
                                               __bf16* __restrict__ Bt, int K, int kbits) {
  int id = blockIdx.x * 256 + threadIdx.x;  // 256*K total
  int k = id & (K - 1);
  int n = id >> kbits;
  float v = (n < DH) ? W[(size_t)k * DH + n] : Wr[(size_t)k * DH + (n - DH)];
  Bt[(size_t)n * K + k] = (__bf16)v;
}

// ---------------- MFMA GEMM v2 ----------------
// BM=64 x BN=256 (cols 0..127 -> XW, 128..255 -> RES), BK=64, 512 thr = 8 waves (2x4).
// A: double-buffered LDS via global_load_lds with XOR chunk-swizzled SOURCE (linear dest),
//    fp32 stored as fp32, cvt to bf16 at fragment read.
// B: no LDS -- per-lane 16B fragment loads straight from Bt (L2-resident, 576KB total).
// One __syncthreads per k-step; stage(k+1) issued before compute(k).
__device__ __forceinline__ void load_lds16(const void* g, void* l) {
  __builtin_amdgcn_global_load_lds(
      (const __attribute__((address_space(1))) unsigned int*)g,
      (__attribute__((address_space(3))) unsigned int*)l, 16, 0, 0);
}

template <typename AT, int K>
__global__ __launch_bounds__(512, 4) void k_gemm_mfma(
    const AT* __restrict__ X, const __bf16* __restrict__ Bt,
    const float* __restrict__ br, __bf16* __restrict__ XW,
    float* __restrict__ RES, int M) {
  __shared__ alignas(16) char smem[32768];  // A dbuf (2x16KB fp32 / 2x8KB bf16); epi Cb 32KB
  const int tid = threadIdx.x;
  const int lane = tid & 63;
  const int w = tid >> 6;   // 0..7
  const int wr = w >> 2;    // row half (32 rows)
  const int wc = w & 3;     // col quarter (64 cols)
  const int l15 = lane & 15;
  const int quad = lane >> 4;
  const int bm0 = blockIdx.x * 64;
  constexpr int ROWB = (sizeof(AT) == 4) ? 256 : 128;  // bytes per A-row in LDS
  constexpr int ABUF = 64 * ROWB;

  // stage A tile (64 x 64) for k0 into buffer buf; linear LDS dest, swizzled global src
  auto stageA = [&](int buf, int k0) {
    char* dst = smem + buf * ABUF;
    if constexpr (sizeof(AT) == 4) {
#pragma unroll
      for (int i = 0; i < 2; ++i) {
        const int r = w * 8 + i * 4 + (lane >> 4);  // 4 rows per 1KB issue
        int gr = bm0 + r; if (gr > M - 1) gr = M - 1;
        const int c = (lane & 15) ^ (r & 7);        // 16B chunk (4 floats)
        load_lds16((const char*)X + ((size_t)gr * K + k0 + c * 4) * 4,
                   dst + (w * 8 + i * 4) * 256);
      }
    } else {
      const int r = w * 8 + (lane >> 3);            // 8 rows per 1KB issue
      int gr = bm0 + r; if (gr > M - 1) gr = M - 1;
      const int c = (lane & 7) ^ (r & 7);           // 16B chunk (8 bf16)
      load_lds16((const char*)X + ((size_t)gr * K + k0 + c * 8) * 2,
                 dst + w * 8 * 128);
    }
  };

  // read A fragment (row r = wr*32+mt*16+l15, k slice ks*32+quad*8..+8) as bf16x8
  auto readA = [&](int buf, int mt, int ks) -> bf16x8 {
    const int r = wr * 32 + mt * 16 + l15;
    const char* rowp = smem + buf * ABUF + r * ROWB;
    if constexpr (sizeof(AT) == 4) {
      const int x = r & 7;
      const int c0 = ks * 8 + quad * 2;  // first of two 16B chunks
      const floatx4 u = *(const floatx4*)(rowp + ((c0 ^ x) << 4));
      const floatx4 v = *(const floatx4*)(rowp + (((c0 + 1) ^ x) << 4));
      bf16x8 h;
      h[0] = (__bf16)u[0]; h[1] = (__bf16)u[1]; h[2] = (__bf16)u[2]; h[3] = (__bf16)u[3];
      h[4] = (__bf16)v[0]; h[5] = (__bf16)v[1]; h[6] = (__bf16)v[2]; h[7] = (__bf16)v[3];
      return h;
    } else {
      const int cc = ks * 4 + quad;
      return *(const bf16x8*)(rowp + ((cc ^ (r & 7)) << 4));
    }
  };

  floatx4 acc[2][4];
#pragma unroll
  for (int i = 0; i < 2; ++i)
#pragma unroll
    for (int j = 0; j < 4; ++j) acc[i][j] = (floatx4)0.f;

  stageA(0, 0);
  __syncthreads();

  constexpr int NS = K / 64;
  for (int s = 0; s < NS; ++s) {
    const int k0 = s * 64;
    const int buf = s & 1;
    if (s + 1 < NS) stageA(buf ^ 1, k0 + 64);  // prefetch next tile (other buffer)
#pragma unroll
    for (int ks = 0; ks < 2; ++ks) {
      const bf16x8 a0 = readA(buf, 0, ks);
      const bf16x8 a1 = readA(buf, 1, ks);
#pragma unroll
      for (int nt = 0; nt < 4; ++nt) {
        const int n = wc * 64 + nt * 16 + l15;
        const bf16x8 bfrag =
            *(const bf16x8*)(Bt + (size_t)n * K + k0 + ks * 32 + quad * 8);
        acc[0][nt] = __builtin_amdgcn_mfma_f32_16x16x32_bf16(a0, bfrag, acc[0][nt], 0, 0, 0);
        acc[1][nt] = __builtin_amdgcn_mfma_f32_16x16x32_bf16(a1, bfrag, acc[1][nt], 0, 0, 0);
      }
    }
    __syncthreads();  // reads of buf done; stage into buf^1 drained
  }

  // --- epilogue: 2 passes of 32 rows through Cb (32KB, reuses A buffers) ---
  float* Cb = (float*)smem;
#pragma unroll
  for (int half = 0; half < 2; ++half) {
    if (wr == half) {
#pragma unroll
      for (int mt = 0; mt < 2; ++mt)
#pragma unroll
        for (int nt = 0; nt < 4; ++nt)
#pragma unroll
          for (int r = 0; r < 4; ++r)
            Cb[(mt * 16 + quad * 4 + r) * 256 + wc * 64 + nt * 16 + l15] = acc[mt][nt][r];
    }
    __syncthreads();
    const int row = tid >> 4;   // 0..31
    const int seg = tid & 15;   // 0..15
    const int grow = bm0 + half * 32 + row;
    if (grow < M) {
      if (seg < 8) {  // XW cols seg*16..+15 -> bf16
        const int c0 = seg * 16;
#pragma unroll
        for (int j = 0; j < 2; ++j) {
          const float4 v0 = *(const float4*)&Cb[row * 256 + c0 + j * 8];
          const float4 v1 = *(const float4*)&Cb[row * 256 + c0 + j * 8 + 4];
          bf16x8 h;
          h[0] = (__bf16)v0.x; h[1] = (__bf16)v0.y; h[2] = (__bf16)v0.z; h[3] = (__bf16)v0.w;
          h[4] = (__bf16)v1.x; h[5] = (__bf16)v1.y; h[6] = (__bf16)v1.z; h[7] = (__bf16)v1.w;
          *(bf16x8*)&XW[(size_t)grow * DH + c0 + j * 8] = h;
        }
      } else {  // RES cols (seg-8)*16..+15 -> relu(x+br) f32
        const int c0 = (seg - 8) * 16;
#pragma unroll
        for (int j = 0; j < 4; ++j) {
          const float4 v = *(const float4*)&Cb[row * 256 + 128 + c0 + j * 4];
          const float4 bb = *(const float4*)&br[c0 + j * 4];
          *(float4*)&RES[(size_t)grow * DH + c0 + j * 4] =
              make_float4(fmaxf(v.x + bb.x, 0.f), fmaxf(v.y + bb.y, 0.f),
                          fmaxf(v.z + bb.z, 0.f), fmaxf(v.w + bb.w, 0.f));
        }
      }
    }
    __syncthreads();
  }
}

// ---------------- aggregation + bias + relu + residual + BN (+ fused head) ----------------
// one wave per node; lane handles feature pair (2*lane, 2*lane+1).
// MODE 0: write h as bf16 pairs. MODE 1: fused head -> softmax out.
template <int MODE>
__global__ __launch_bounds__(256) void k_agg2(
    const __bf16* __restrict__ XW, const float* __restrict__ RES,
    const int* __restrict__ row_ptr, const int* __restrict__ csr_src,
    const float* __restrict__ b, const float* __restrict__ gamma,
    const float* __restrict__ beta, const float* __restrict__ mean,
    const float* __restrict__ var, const float* __restrict__ Wd,
    const float* __restrict__ bd, void* __restrict__ hout, int M) {
  const int node = (blockIdx.x << 2) + (threadIdx.x >> 6);
  const int lane = threadIdx.x & 63;
  if (node >= M) return;
  const int s = row_ptr[node], e = row_ptr[node + 1];
  const unsigned* xw = (const unsigned*)XW;  // 64 uints per row = 128 bf16
  float ax = 0.f, ay = 0.f;
  int i = s;
  for (; i + 3 < e; i += 4) {
    const int s0 = csr_src[i], s1 = csr_src[i + 1], s2 = csr_src[i + 2], s3 = csr_src[i + 3];
    const unsigned u0 = xw[(size_t)s0 * 64 + lane];
    const unsigned u1 = xw[(size_t)s1 * 64 + lane];
    const unsigned u2 = xw[(size_t)s2 * 64 + lane];
    const unsigned u3 = xw[(size_t)s3 * 64 + lane];
    ax += __uint_as_float(u0 << 16) + __uint_as_float(u1 << 16) +
          __uint_as_float(u2 << 16) + __uint_as_float(u3 << 16);
    ay += __uint_as_float(u0 & 0xffff0000u) + __uint_as_float(u1 & 0xffff0000u) +
          __uint_as_float(u2 & 0xffff0000u) + __uint_as_float(u3 & 0xffff0000u);
  }
  for (; i < e; ++i) {
    const unsigned u = xw[(size_t)csr_src[i] * 64 + lane];
    ax += __uint_as_float(u << 16);
    ay += __uint_as_float(u & 0xffff0000u);
  }
  const int f0 = lane << 1;
  const float2 bb = *(const float2*)&b[f0];
  const float2 rr = *(const float2*)&RES[(size_t)node * DH + f0];
  const float2 mm = *(const float2*)&mean[f0];
  const float2 vv = *(const float2*)&var[f0];
  const float2 gg = *(const float2*)&gamma[f0];
  const float2 be = *(const float2*)&beta[f0];
  const float x0 = fmaxf(ax + bb.x, 0.f) + rr.x;
  const float x1 = fmaxf(ay + bb.y, 0.f) + rr.y;
  const float y0 = (x0 - mm.x) * rsqrtf(vv.x + 1e-5f) * gg.x + be.x;
  const float y1 = (x1 - mm.y) * rsqrtf(vv.y + 1e-5f) * gg.y + be.y;
  if (MODE == 0) {
    union { __bf16 h[2]; unsigned u; } pk;
    pk.h[0] = (__bf16)y0;
    pk.h[1] = (__bf16)y1;
    ((unsigned*)hout)[(size_t)node * 64 + lane] = pk.u;
  } else {
    const float4 wv = *(const float4*)&Wd[f0 * 2];  // Wd[f0][0,1], Wd[f0+1][0,1]
    float l0 = y0 * wv.x + y1 * wv.z;
    float l1 = y0 * wv.y + y1 * wv.w;
#pragma unroll
    for (int off = 32; off > 0; off >>= 1) {
      l0 += __shfl_down(l0, off);
      l1 += __shfl_down(l1, off);
    }
    if (lane == 0) {
      l0 += bd[0];
      l1 += bd[1];
      const float m = fmaxf(l0, l1);
      const float e0 = expf(l0 - m), e1 = expf(l1 - m);
      const float inv = 1.f / (e0 + e1);
      float* out = (float*)hout;
      out[(size_t)node * 2] = e0 * inv;
      out[(size_t)node * 2 + 1] = e1 * inv;
    }
  }
}

// ---------------- launch ----------------
extern "C" void kernel_launch(void* const* d_in, const int* in_sizes, int n_in,
                              void* d_out, int out_size, void* d_ws, size_t ws_size,
                              hipStream_t stream) {
  const float* in_feat = (const float*)d_in[0];
  const int* src = (const int*)d_in[1];
  const int* dst = (const int*)d_in[2];
  const float* W0 = (const float*)d_in[3];
  const float* b0 = (const float*)d_in[4];
  const float* Wr0 = (const float*)d_in[5];
  const float* br0 = (const float*)d_in[6];
  const float* gamma0 = (const float*)d_in[7];
  const float* beta0 = (const float*)d_in[8];
  const float* mean0 = (const float*)d_in[9];
  const float* var0 = (const float*)d_in[10];
  const float* W1 = (const float*)d_in[11];
  const float* b1 = (const float*)d_in[12];
  const float* Wr1 = (const float*)d_in[13];
  const float* br1 = (const float*)d_in[14];
  const float* gamma1 = (const float*)d_in[15];
  const float* beta1 = (const float*)d_in[16];
  const float* mean1 = (const float*)d_in[17];
  const float* var1 = (const float*)d_in[18];
  const float* Wd = (const float*)d_in[19];
  const float* bd = (const float*)d_in[20];
  float* out = (float*)d_out;

  char* ws = (char*)d_ws;
  size_t off = 0;
  auto alloc = [&](size_t bytes) {
    void* p = ws + off;
    off += (bytes + 255) & ~(size_t)255;
    return p;
  };
  __bf16* XWb = (__bf16*)alloc(sizeof(__bf16) * (size_t)NNODES * DH);  // 12.8 MB
  __bf16* h1 = (__bf16*)alloc(sizeof(__bf16) * (size_t)NNODES * DH);   // 12.8 MB
  float* RES = (float*)alloc(sizeof(float) * (size_t)NNODES * DH);     // 25.6 MB
  int* cnt = (int*)alloc(sizeof(int) * NNODES);
  int* cursor = (int*)alloc(sizeof(int) * NNODES);
  int* row_ptr = (int*)alloc(sizeof(int) * (NNODES + 1));
  int* csr_src = (int*)alloc(sizeof(int) * NEDGES);
  int* bsum = (int*)alloc(sizeof(int) * 64);
  int* boff = (int*)alloc(sizeof(int) * 64);
  __bf16* Bt0 = (__bf16*)alloc(sizeof(__bf16) * 256 * KIN);
  __bf16* Bt1 = (__bf16*)alloc(sizeof(__bf16) * 256 * DH);

  const int nb = (NNODES + 1023) / 1024;  // 49
  // CSR build
  k_zero2<<<(NNODES + 255) / 256, 256, 0, stream>>>(cnt, cursor, NNODES);
  k_hist<<<(NEDGES + 255) / 256, 256, 0, stream>>>(dst, cnt, NEDGES);
  k_scan_local<<<nb, 1024, 0, stream>>>(cnt, row_ptr, bsum, NNODES);
  k_scan_sums<<<1, 64, 0, stream>>>(bsum, boff, nb, row_ptr, NNODES);
  k_scan_add<<<(NNODES + 255) / 256, 256, 0, stream>>>(row_ptr, boff, NNODES);
  k_fill<<<(NEDGES + 255) / 256, 256, 0, stream>>>(src, dst, row_ptr, cursor, csr_src, NEDGES);

  // weight pre-convert
  k_prepB<<<KIN, 256, 0, stream>>>(W0, Wr0, Bt0, KIN, 10);
  k_prepB<<<DH, 256, 0, stream>>>(W1, Wr1, Bt1, DH, 7);

  const int ggrid = (NNODES + 63) / 64;
  const int agrid = (NNODES + 3) / 4;
  // layer 0
  k_gemm_mfma<float, KIN><<<ggrid, 512, 0, stream>>>(in_feat, Bt0, br0, XWb, RES, NNODES);
  k_agg2<0><<<agrid, 256, 0, stream>>>(XWb, RES, row_ptr, csr_src, b0, gamma0, beta0,
                                       mean0, var0, nullptr, nullptr, h1, NNODES);
  // layer 1 (+ fused head)
  k_gemm_mfma<__bf16, DH><<<ggrid, 512, 0, stream>>>(h1, Bt1, br1, XWb, RES, NNODES);
  k_agg2<1><<<agrid, 256, 0, stream>>>(XWb, RES, row_ptr, csr_src, b1, gamma1, beta1,
                                       mean1, var1, Wd, bd, out, NNODES);
}

// Round 4
// 551.453 us; speedup vs baseline: 1.1220x; 1.1220x over previous
//
#include <hip/hip_runtime.h>
#include <math.h>

#define NNODES 50000
#define NEDGES 800000
#define KIN 1024
#define DH 128

typedef __bf16 bf16x8 __attribute__((ext_vector_type(8)));
typedef float floatx4 __attribute__((ext_vector_type(4)));

// ---------------- CSR build ----------------
__global__ void k_zero2(int* __restrict__ a, int* __restrict__ b, int n) {
  int i = blockIdx.x * blockDim.x + threadIdx.x;
  if (i < n) { a[i] = 0; b[i] = 0; }
}

__global__ void k_hist(const int* __restrict__ dst, int* __restrict__ cnt, int E) {
  int i = blockIdx.x * blockDim.x + threadIdx.x;
  if (i < E) atomicAdd(&cnt[dst[i]], 1);
}

// hierarchical scan: per-block 1024-elem scan + block sums
__global__ __launch_bounds__(1024) void k_scan_local(const int* __restrict__ cnt,
                                                     int* __restrict__ row_ptr,
                                                     int* __restrict__ bsum, int n) {
  __shared__ int sd[1024];
  int t = threadIdx.x;
  int i = blockIdx.x * 1024 + t;
  int v = (i < n) ? cnt[i] : 0;
  sd[t] = v;
  __syncthreads();
  for (int off = 1; off < 1024; off <<= 1) {
    int tv = (t >= off) ? sd[t - off] : 0;
    __syncthreads();
    sd[t] += tv;
    __syncthreads();
  }
  if (i < n) row_ptr[i] = sd[t] - v;  // exclusive within block
  if (t == 1023) bsum[blockIdx.x] = sd[t];
}

// one wave scans the <=64 block sums; writes exclusive offsets + grand total
__global__ void k_scan_sums(const int* __restrict__ bsum, int* __restrict__ boff,
                            int nb, int* __restrict__ row_ptr, int n) {
  int lane = threadIdx.x;  // 64 threads
  int v = (lane < nb) ? bsum[lane] : 0;
  int incl = v;
  for (int off = 1; off < 64; off <<= 1) {
    int t = __shfl_up(incl, off);
    if (lane >= off) incl += t;
  }
  boff[lane] = incl - v;
  if (lane == 63) row_ptr[n] = incl;
}

__global__ void k_scan_add(int* __restrict__ row_ptr, const int* __restrict__ boff, int n) {
  int i = blockIdx.x * blockDim.x + threadIdx.x;
  if (i < n) row_ptr[i] += boff[i >> 10];
}

__global__ void k_fill(const int* __restrict__ src, const int* __restrict__ dst,
                       const int* __restrict__ row_ptr, int* __restrict__ cursor,
                       int* __restrict__ csr_src, int E) {
  int i = blockIdx.x * blockDim.x + threadIdx.x;
  if (i < E) {
    int d = dst[i];
    int pos = row_ptr[d] + atomicAdd(&cursor[d], 1);
    csr_src[pos] = src[i];
  }
}

// ---------------- B pre-convert: Bt[256][K] bf16, Bt[n][k] = (W|Wr)[k][n] ----------------
__global__ __launch_bounds__(256) void k_prepB(const float* __restrict__ W,
                                               const float* __restrict__ Wr,
                                               __bf16* __restrict__ Bt, int K, int kbits) {
  int id = blockIdx.x * 256 + threadIdx.x;  // 256*K total
  int k = id & (K - 1);
  int n = id >> kbits;
  float v = (n < DH) ? W[(size_t)k * DH + n] : Wr[(size_t)k * DH + (n - DH)];
  Bt[(size_t)n * K + k] = (__bf16)v;
}

// ---------------- MFMA GEMM v3 ----------------
// BM=64 x BN=256 (cols 0..127 -> XW, 128..255 -> RES), BK=64, 512 thr = 8 waves (2x4).
// A and B both staged to LDS via global_load_lds (XOR chunk-swizzled source, linear dest).
// 3-buffer pipeline, prefetch depth 2, counted vmcnt across raw s_barrier (T3+T4):
//   prologue: stage(0), stage(1)
//   step s:   vmcnt(L) [vmcnt(0) if last] ; s_barrier ; stage(s+2) ; compute(s)
// L = this wave's loads for ONE tile (A:2 + B:4 = 6 fp32 / 1+4 = 5 bf16).
__device__ __forceinline__ void load_lds16(const void* g, void* l) {
  __builtin_amdgcn_global_load_lds(
      (const __attribute__((address_space(1))) unsigned int*)g,
      (__attribute__((address_space(3))) unsigned int*)l, 16, 0, 0);
}

#define WAITV(N) asm volatile("s_waitcnt vmcnt(" #N ")" ::: "memory")

template <typename AT, int K>
__global__ __launch_bounds__(512, 2) void k_gemm_mfma(
    const AT* __restrict__ X, const __bf16* __restrict__ Bt,
    const float* __restrict__ br, __bf16* __restrict__ XW,
    float* __restrict__ RES, int M) {
  constexpr int ROWB = (sizeof(AT) == 4) ? 256 : 128;  // bytes per A-row in LDS
  constexpr int ABUF = 64 * ROWB;                      // 16KB fp32 / 8KB bf16
  constexpr int BBUF = 256 * 64 * 2;                   // 32KB
  constexpr int TBUF = ABUF + BBUF;
  __shared__ alignas(16) char smem[3 * TBUF];  // 144KB fp32 / 120KB bf16
  const int tid = threadIdx.x;
  const int lane = tid & 63;
  const int w = tid >> 6;   // 0..7
  const int wr = w >> 2;    // row half (32 rows)
  const int wc = w & 3;     // col quarter (64 cols)
  const int l15 = lane & 15;
  const int quad = lane >> 4;
  const int bm0 = blockIdx.x * 64;

  // stage A tile (64 x BK=64) into abase; linear LDS dest, swizzled global src
  auto stageA = [&](char* abase, int k0) {
    if constexpr (sizeof(AT) == 4) {
#pragma unroll
      for (int i = 0; i < 2; ++i) {
        const int r = w * 8 + i * 4 + (lane >> 4);  // 4 rows per 1KB issue
        int gr = bm0 + r; if (gr > M - 1) gr = M - 1;
        const int c = (lane & 15) ^ (r & 7);        // 16B chunk (4 floats)
        load_lds16((const char*)X + ((size_t)gr * K + k0 + c * 4) * 4,
                   abase + (w * 8 + i * 4) * 256);
      }
    } else {
      const int r = w * 8 + (lane >> 3);            // 8 rows per 1KB issue
      int gr = bm0 + r; if (gr > M - 1) gr = M - 1;
      const int c = (lane & 7) ^ (r & 7);           // 16B chunk (8 bf16)
      load_lds16((const char*)X + ((size_t)gr * K + k0 + c * 8) * 2,
                 abase + w * 8 * 128);
    }
  };
  // stage B tile (256 x 64) into bbase; 4 issues/wave, XOR chunk swizzle on source
  auto stageB = [&](char* bbase, int k0) {
#pragma unroll
    for (int ii = 0; ii < 4; ++ii) {
      const int wi = ii * 8 + w;            // 0..31 -> dst bbase + wi*1024
      const int n = wi * 8 + (lane >> 3);   // 0..255
      const int c = lane & 7;               // dst 16B chunk in row
      const int cs = c ^ (n & 7);           // src chunk (bank swizzle)
      load_lds16((const char*)Bt + (size_t)n * (K * 2) + (size_t)k0 * 2 + cs * 16,
                 bbase + wi * 1024);
    }
  };
  auto stage = [&](int s) {
    char* base = smem + (s % 3) * TBUF;
    stageA(base, s * 64);
    stageB(base + ABUF, s * 64);
  };

  // read A fragment (row r = wr*32+mt*16+l15, k slice ks*32+quad*8..+8) as bf16x8
  auto readA = [&](const char* abase, int mt, int ks) -> bf16x8 {
    const int r = wr * 32 + mt * 16 + l15;
    const char* rowp = abase + r * ROWB;
    if constexpr (sizeof(AT) == 4) {
      const int x = r & 7;
      const int c0 = ks * 8 + quad * 2;  // first of two 16B chunks
      const floatx4 u = *(const floatx4*)(rowp + ((c0 ^ x) << 4));
      const floatx4 v = *(const floatx4*)(rowp + (((c0 + 1) ^ x) << 4));
      bf16x8 h;
      h[0] = (__bf16)u[0]; h[1] = (__bf16)u[1]; h[2] = (__bf16)u[2]; h[3] = (__bf16)u[3];
      h[4] = (__bf16)v[0]; h[5] = (__bf16)v[1]; h[6] = (__bf16)v[2]; h[7] = (__bf16)v[3];
      return h;
    } else {
      const int cc = ks * 4 + quad;
      return *(const bf16x8*)(rowp + ((cc ^ (r & 7)) << 4));
    }
  };
  auto readB = [&](const char* bbase, int nt, int ks) -> bf16x8 {
    const int n = wc * 64 + nt * 16 + l15;
    const int ch = (ks * 4 + quad) ^ (n & 7);
    return *(const bf16x8*)(bbase + n * 128 + ch * 16);
  };

  floatx4 acc[2][4];
#pragma unroll
  for (int i = 0; i < 2; ++i)
#pragma unroll
    for (int j = 0; j < 4; ++j) acc[i][j] = (floatx4)0.f;

  constexpr int NS = K / 64;  // >= 2 always
  stage(0);
  stage(1);

  for (int s = 0; s < NS; ++s) {
    if (s == NS - 1) {
      WAITV(0);
    } else if constexpr (sizeof(AT) == 4) {
      WAITV(6);
    } else {
      WAITV(5);
    }
    __builtin_amdgcn_s_barrier();
    __builtin_amdgcn_sched_barrier(0);
    if (s + 2 < NS) stage(s + 2);
    const char* abase = smem + (s % 3) * TBUF;
    const char* bbase = abase + ABUF;
    bf16x8 af[2][2], bfr[4][2];
#pragma unroll
    for (int mt = 0; mt < 2; ++mt)
#pragma unroll
      for (int ks = 0; ks < 2; ++ks) af[mt][ks] = readA(abase, mt, ks);
#pragma unroll
    for (int nt = 0; nt < 4; ++nt)
#pragma unroll
      for (int ks = 0; ks < 2; ++ks) bfr[nt][ks] = readB(bbase, nt, ks);
#pragma unroll
    for (int ks = 0; ks < 2; ++ks)
#pragma unroll
      for (int mt = 0; mt < 2; ++mt)
#pragma unroll
        for (int nt = 0; nt < 4; ++nt)
          acc[mt][nt] = __builtin_amdgcn_mfma_f32_16x16x32_bf16(af[mt][ks], bfr[nt][ks],
                                                                acc[mt][nt], 0, 0, 0);
  }
  __syncthreads();  // full drain before smem reuse as Cb

  // --- epilogue: 2 passes of 32 rows through Cb (32KB at smem base) ---
  float* Cb = (float*)smem;
#pragma unroll
  for (int half = 0; half < 2; ++half) {
    if (wr == half) {
#pragma unroll
      for (int mt = 0; mt < 2; ++mt)
#pragma unroll
        for (int nt = 0; nt < 4; ++nt)
#pragma unroll
          for (int r = 0; r < 4; ++r)
            Cb[(mt * 16 + quad * 4 + r) * 256 + wc * 64 + nt * 16 + l15] = acc[mt][nt][r];
    }
    __syncthreads();
    const int row = tid >> 4;   // 0..31
    const int seg = tid & 15;   // 0..15
    const int grow = bm0 + half * 32 + row;
    if (grow < M) {
      if (seg < 8) {  // XW cols seg*16..+15 -> bf16
        const int c0 = seg * 16;
#pragma unroll
        for (int j = 0; j < 2; ++j) {
          const float4 v0 = *(const float4*)&Cb[row * 256 + c0 + j * 8];
          const float4 v1 = *(const float4*)&Cb[row * 256 + c0 + j * 8 + 4];
          bf16x8 h;
          h[0] = (__bf16)v0.x; h[1] = (__bf16)v0.y; h[2] = (__bf16)v0.z; h[3] = (__bf16)v0.w;
          h[4] = (__bf16)v1.x; h[5] = (__bf16)v1.y; h[6] = (__bf16)v1.z; h[7] = (__bf16)v1.w;
          *(bf16x8*)&XW[(size_t)grow * DH + c0 + j * 8] = h;
        }
      } else {  // RES cols (seg-8)*16..+15 -> relu(x+br) f32
        const int c0 = (seg - 8) * 16;
#pragma unroll
        for (int j = 0; j < 4; ++j) {
          const float4 v = *(const float4*)&Cb[row * 256 + 128 + c0 + j * 4];
          const float4 bb = *(const float4*)&br[c0 + j * 4];
          *(float4*)&RES[(size_t)grow * DH + c0 + j * 4] =
              make_float4(fmaxf(v.x + bb.x, 0.f), fmaxf(v.y + bb.y, 0.f),
                          fmaxf(v.z + bb.z, 0.f), fmaxf(v.w + bb.w, 0.f));
        }
      }
    }
    __syncthreads();
  }
}

// ---------------- aggregation + bias + relu + residual + BN (+ fused head) ----------------
// one wave per node; lane handles feature pair (2*lane, 2*lane+1).
// MODE 0: write h as bf16 pairs. MODE 1: fused head -> softmax out.
template <int MODE>
__global__ __launch_bounds__(256) void k_agg2(
    const __bf16* __restrict__ XW, const float* __restrict__ RES,
    const int* __restrict__ row_ptr, const int* __restrict__ csr_src,
    const float* __restrict__ b, const float* __restrict__ gamma,
    const float* __restrict__ beta, const float* __restrict__ mean,
    const float* __restrict__ var, const float* __restrict__ Wd,
    const float* __restrict__ bd, void* __restrict__ hout, int M) {
  const int node = (blockIdx.x << 2) + (threadIdx.x >> 6);
  const int lane = threadIdx.x & 63;
  if (node >= M) return;
  const int s = row_ptr[node], e = row_ptr[node + 1];
  const unsigned* xw = (const unsigned*)XW;  // 64 uints per row = 128 bf16
  float ax = 0.f, ay = 0.f;
  int i = s;
  for (; i + 3 < e; i += 4) {
    const int s0 = csr_src[i], s1 = csr_src[i + 1], s2 = csr_src[i + 2], s3 = csr_src[i + 3];
    const unsigned u0 = xw[(size_t)s0 * 64 + lane];
    const unsigned u1 = xw[(size_t)s1 * 64 + lane];
    const unsigned u2 = xw[(size_t)s2 * 64 + lane];
    const unsigned u3 = xw[(size_t)s3 * 64 + lane];
    ax += __uint_as_float(u0 << 16) + __uint_as_float(u1 << 16) +
          __uint_as_float(u2 << 16) + __uint_as_float(u3 << 16);
    ay += __uint_as_float(u0 & 0xffff0000u) + __uint_as_float(u1 & 0xffff0000u) +
          __uint_as_float(u2 & 0xffff0000u) + __uint_as_float(u3 & 0xffff0000u);
  }
  for (; i < e; ++i) {
    const unsigned u = xw[(size_t)csr_src[i] * 64 + lane];
    ax += __uint_as_float(u << 16);
    ay += __uint_as_float(u & 0xffff0000u);
  }
  const int f0 = lane << 1;
  const float2 bb = *(const float2*)&b[f0];
  const float2 rr = *(const float2*)&RES[(size_t)node * DH + f0];
  const float2 mm = *(const float2*)&mean[f0];
  const float2 vv = *(const float2*)&var[f0];
  const float2 gg = *(const float2*)&gamma[f0];
  const float2 be = *(const float2*)&beta[f0];
  const float x0 = fmaxf(ax + bb.x, 0.f) + rr.x;
  const float x1 = fmaxf(ay + bb.y, 0.f) + rr.y;
  const float y0 = (x0 - mm.x) * rsqrtf(vv.x + 1e-5f) * gg.x + be.x;
  const float y1 = (x1 - mm.y) * rsqrtf(vv.y + 1e-5f) * gg.y + be.y;
  if (MODE == 0) {
    union { __bf16 h[2]; unsigned u; } pk;
    pk.h[0] = (__bf16)y0;
    pk.h[1] = (__bf16)y1;
    ((unsigned*)hout)[(size_t)node * 64 + lane] = pk.u;
  } else {
    const float4 wv = *(const float4*)&Wd[f0 * 2];  // Wd[f0][0,1], Wd[f0+1][0,1]
    float l0 = y0 * wv.x + y1 * wv.z;
    float l1 = y0 * wv.y + y1 * wv.w;
#pragma unroll
    for (int off = 32; off > 0; off >>= 1) {
      l0 += __shfl_down(l0, off);
      l1 += __shfl_down(l1, off);
    }
    if (lane == 0) {
      l0 += bd[0];
      l1 += bd[1];
      const float m = fmaxf(l0, l1);
      const float e0 = expf(l0 - m), e1 = expf(l1 - m);
      const float inv = 1.f / (e0 + e1);
      float* out = (float*)hout;
      out[(size_t)node * 2] = e0 * inv;
      out[(size_t)node * 2 + 1] = e1 * inv;
    }
  }
}

// ---------------- launch ----------------
extern "C" void kernel_launch(void* const* d_in, const int* in_sizes, int n_in,
                              void* d_out, int out_size, void* d_ws, size_t ws_size,
                              hipStream_t stream) {
  const float* in_feat = (const float*)d_in[0];
  const int* src = (const int*)d_in[1];
  const int* dst = (const int*)d_in[2];
  const float* W0 = (const float*)d_in[3];
  const float* b0 = (const float*)d_in[4];
  const float* Wr0 = (const float*)d_in[5];
  const float* br0 = (const float*)d_in[6];
  const float* gamma0 = (const float*)d_in[7];
  const float* beta0 = (const float*)d_in[8];
  const float* mean0 = (const float*)d_in[9];
  const float* var0 = (const float*)d_in[10];
  const float* W1 = (const float*)d_in[11];
  const float* b1 = (const float*)d_in[12];
  const float* Wr1 = (const float*)d_in[13];
  const float* br1 = (const float*)d_in[14];
  const float* gamma1 = (const float*)d_in[15];
  const float* beta1 = (const float*)d_in[16];
  const float* mean1 = (const float*)d_in[17];
  const float* var1 = (const float*)d_in[18];
  const float* Wd = (const float*)d_in[19];
  const float* bd = (const float*)d_in[20];
  float* out = (float*)d_out;

  char* ws = (char*)d_ws;
  size_t off = 0;
  auto alloc = [&](size_t bytes) {
    void* p = ws + off;
    off += (bytes + 255) & ~(size_t)255;
    return p;
  };
  __bf16* XWb = (__bf16*)alloc(sizeof(__bf16) * (size_t)NNODES * DH);  // 12.8 MB
  __bf16* h1 = (__bf16*)alloc(sizeof(__bf16) * (size_t)NNODES * DH);   // 12.8 MB
  float* RES = (float*)alloc(sizeof(float) * (size_t)NNODES * DH);     // 25.6 MB
  int* cnt = (int*)alloc(sizeof(int) * NNODES);
  int* cursor = (int*)alloc(sizeof(int) * NNODES);
  int* row_ptr = (int*)alloc(sizeof(int) * (NNODES + 1));
  int* csr_src = (int*)alloc(sizeof(int) * NEDGES);
  int* bsum = (int*)alloc(sizeof(int) * 64);
  int* boff = (int*)alloc(sizeof(int) * 64);
  __bf16* Bt0 = (__bf16*)alloc(sizeof(__bf16) * 256 * KIN);
  __bf16* Bt1 = (__bf16*)alloc(sizeof(__bf16) * 256 * DH);

  const int nb = (NNODES + 1023) / 1024;  // 49
  // CSR build
  k_zero2<<<(NNODES + 255) / 256, 256, 0, stream>>>(cnt, cursor, NNODES);
  k_hist<<<(NEDGES + 255) / 256, 256, 0, stream>>>(dst, cnt, NEDGES);
  k_scan_local<<<nb, 1024, 0, stream>>>(cnt, row_ptr, bsum, NNODES);
  k_scan_sums<<<1, 64, 0, stream>>>(bsum, boff, nb, row_ptr, NNODES);
  k_scan_add<<<(NNODES + 255) / 256, 256, 0, stream>>>(row_ptr, boff, NNODES);
  k_fill<<<(NEDGES + 255) / 256, 256, 0, stream>>>(src, dst, row_ptr, cursor, csr_src, NEDGES);

  // weight pre-convert
  k_prepB<<<KIN, 256, 0, stream>>>(W0, Wr0, Bt0, KIN, 10);
  k_prepB<<<DH, 256, 0, stream>>>(W1, Wr1, Bt1, DH, 7);

  const int ggrid = (NNODES + 63) / 64;
  const int agrid = (NNODES + 3) / 4;
  // layer 0
  k_gemm_mfma<float, KIN><<<ggrid, 512, 0, stream>>>(in_feat, Bt0, br0, XWb, RES, NNODES);
  k_agg2<0><<<agrid, 256, 0, stream>>>(XWb, RES, row_ptr, csr_src, b0, gamma0, beta0,
                                       mean0, var0, nullptr, nullptr, h1, NNODES);
  // layer 1 (+ fused head)
  k_gemm_mfma<__bf16, DH><<<ggrid, 512, 0, stream>>>(h1, Bt1, br1, XWb, RES, NNODES);
  k_agg2<1><<<agrid, 256, 0, stream>>>(XWb, RES, row_ptr, csr_src, b1, gamma1, beta1,
                                       mean1, var1, Wd, bd, out, NNODES);
}